// Round 5
// baseline (415.152 us; speedup 1.0000x reference)
//
#include <hip/hip_runtime.h>
#include <hip/hip_bf16.h>

#define NN 100000
#define NP 100096            // 782 * 128, padded row count for GEMM
#define EM 1600000
#define EA 200000
#define ET (EM + EA)
#define SB 98                // scan blocks of 1024: 98*1024 >= NN

#define HC 128               // chunks per histogram
#define CNT_CHUNK 14063      // 128*14063 = 1800064 >= ET
#define DEG_CHUNK 12500      // 128*12500 = EM exactly
#define PITCHW 25024         // dwords per histogram slice (= 100096 B >= NN)
#define PITCHB 100096        // bytes per slice

// ws layout (4B units):
//  norm[NN] | cnt[NN] | cursor[NN] | bsum[128] | Wb[16384] |
//  rec[ET] uint4 | featsb[64*NP] | hist region (2*HC*PITCHW = 64*NP) |
//  rank16[ET] ushort
#define OFF_NORM 0
#define OFF_CNT  (NN)
#define OFF_CUR  (2*NN)
#define OFF_BSUM (3*NN)
#define OFF_WB   (3*NN + 128)
#define OFF_REC  (OFF_WB + 16384)    // 16B-aligned
#define OFF_FB   (OFF_REC + 4*ET)
#define OFF_HIST (OFF_FB + 64*NP)
#define OFF_RANK (OFF_HIST + 64*NP)

#define UNP_LO(u) __uint_as_float((u) << 16)
#define UNP_HI(u) __uint_as_float((u) & 0xFFFF0000u)

typedef __attribute__((ext_vector_type(8))) short bf16x8;
typedef __attribute__((ext_vector_type(4))) float f32x4;

static __device__ __forceinline__ unsigned pack_bf16x2(float a, float b) {
  union { __hip_bfloat162 v; unsigned u; } cv;
  cv.v = __float22bfloat162_rn(make_float2(a, b));
  return cv.u;
}

// Histogram without global atomics (LDS byte counters) + fused feats->bf16
// convert. Blocks 0..127: dst-histogram over edge chunk c; byte-in-word LDS
// atomicAdd old value = local rank. Blocks 128..255: src-histogram (deg).
__global__ __launch_bounds__(1024) void k_hist(
    const int* __restrict__ srcE, const int* __restrict__ dstE,
    const int* __restrict__ dstA, const float* __restrict__ feats,
    unsigned* __restrict__ featsb,
    unsigned* __restrict__ hist8w, unsigned* __restrict__ deg8w,
    unsigned short* __restrict__ rank16) {
  __shared__ unsigned h[PITCHW];
  int tid = threadIdx.x;
  int bid = blockIdx.x;

  // fused convert: grid-stride over NP*64 dwords (2*HC*1024 = 262144 threads)
  for (int i = bid * 1024 + tid; i < NP * 64; i += 2 * HC * 1024) {
    if (i < NN * 64) {
      float2 f = ((const float2*)feats)[i];
      featsb[i] = pack_bf16x2(f.x, f.y);
    } else {
      featsb[i] = 0u;
    }
  }

  for (int i = tid; i < PITCHW; i += 1024) h[i] = 0u;
  __syncthreads();
  if (bid < HC) {
    int c = bid;
    int e1 = c * CNT_CHUNK + CNT_CHUNK; if (e1 > ET) e1 = ET;
    for (int e = c * CNT_CHUNK + tid; e < e1; e += 1024) {
      int d = (e < EM) ? dstE[e] : dstA[e - EM];
      unsigned sh = 8u * (unsigned)(d & 3);
      unsigned old = atomicAdd(&h[d >> 2], 1u << sh);
      unsigned lr = (old >> sh) & 255u;
      rank16[e] = (unsigned short)(((unsigned)c << 9) | lr);
    }
    __syncthreads();
    unsigned* dst = hist8w + (size_t)c * PITCHW;
    for (int i = tid; i < PITCHW; i += 1024) dst[i] = h[i];
  } else {
    int c = bid - HC;
    int e1 = c * DEG_CHUNK + DEG_CHUNK;
    for (int e = c * DEG_CHUNK + tid; e < e1; e += 1024) {
      int s = srcE[e];
      atomicAdd(&h[s >> 2], 1u << (8u * (unsigned)(s & 3)));
    }
    __syncthreads();
    unsigned* dst = deg8w + (size_t)c * PITCHW;
    for (int i = tid; i < PITCHW; i += 1024) dst[i] = h[i];
  }
}

// Per node: exclusive prefix over the 128 cnt byte-slices (in place -> per-
// chunk bases), total -> cnt; sum deg slices -> norm = rsqrt. Also builds Wb.
__global__ __launch_bounds__(256) void k_merge_wt(
    unsigned char* __restrict__ hist8, const unsigned char* __restrict__ deg8,
    unsigned* __restrict__ cnt, float* __restrict__ norm,
    const float* __restrict__ Wmsg, const float* __restrict__ Wskip,
    unsigned* __restrict__ Wb) {
  int i = blockIdx.x * 256 + threadIdx.x;
  if (i < NN) {
    unsigned t = 0;
    for (int c = 0; c < HC; ++c) {
      unsigned char* p = hist8 + (size_t)c * PITCHB + i;
      unsigned b = *p;
      *p = (unsigned char)t;
      t += b;
    }
    cnt[i] = t;
    unsigned dg = 0;
    for (int c = 0; c < HC; ++c) dg += deg8[(size_t)c * PITCHB + i];
    norm[i] = dg ? rsqrtf((float)dg) : 0.0f;
  }
  if (i < 16384) {
    int j = i >> 7, kk = i & 127;   // kk = uint index within row (2 bf16)
    float a, b;
    if (kk < 64) {
      a = Wmsg[j * 128 + 2 * kk];
      b = Wmsg[j * 128 + 2 * kk + 1];
    } else {
      a = Wskip[j * 128 + 2 * kk - 128];
      b = Wskip[j * 128 + 2 * kk - 127];
    }
    Wb[j * 128 + kk] = pack_bf16x2(a, b);
  }
}

__global__ __launch_bounds__(1024) void k_scan1(const unsigned* __restrict__ cnt,
                                                int* __restrict__ bsum) {
  __shared__ int ws16[16];
  int tid = threadIdx.x, lane = tid & 63, wid = tid >> 6;
  int i = blockIdx.x * 1024 + tid;
  int v = (i < NN) ? (int)cnt[i] : 0;
#pragma unroll
  for (int s = 1; s < 64; s <<= 1) v += __shfl_xor(v, s, 64);
  if (lane == 0) ws16[wid] = v;
  __syncthreads();
  if (tid == 0) {
    int a = 0;
#pragma unroll
    for (int w = 0; w < 16; ++w) a += ws16[w];
    bsum[blockIdx.x] = a;
  }
}

__global__ __launch_bounds__(64) void k_scan2(int* __restrict__ bsum) {
  int lane = threadIdx.x;
  int v0 = (lane < SB) ? bsum[lane] : 0;
  int v1 = (64 + lane < SB) ? bsum[64 + lane] : 0;
  int x0 = v0, x1 = v1;
#pragma unroll
  for (int s = 1; s < 64; s <<= 1) {
    int y = __shfl_up(x0, s, 64); if (lane >= s) x0 += y;
  }
#pragma unroll
  for (int s = 1; s < 64; s <<= 1) {
    int y = __shfl_up(x1, s, 64); if (lane >= s) x1 += y;
  }
  int t0 = __shfl(x0, 63, 64);
  if (lane < SB) bsum[lane] = x0 - v0;
  if (64 + lane < SB) bsum[64 + lane] = t0 + x1 - v1;
}

__global__ __launch_bounds__(1024) void k_scan3(const unsigned* __restrict__ cnt,
                                                const int* __restrict__ bsum,
                                                int* __restrict__ cursor) {
  __shared__ int ws16[16];
  int tid = threadIdx.x, lane = tid & 63, wid = tid >> 6;
  int i = blockIdx.x * 1024 + tid;
  int v = (i < NN) ? (int)cnt[i] : 0;
  int x = v;
#pragma unroll
  for (int s = 1; s < 64; s <<= 1) {
    int y = __shfl_up(x, s, 64); if (lane >= s) x += y;
  }
  if (lane == 63) ws16[wid] = x;
  __syncthreads();
  if (tid == 0) {
    int a = bsum[blockIdx.x];
#pragma unroll
    for (int w = 0; w < 16; ++w) { int t = ws16[w]; ws16[w] = a; a += t; }
  }
  __syncthreads();
  if (i < NN) cursor[i] = ws16[wid] + x - v;   // exclusive start of bucket
}

// bucket by dst, atomic-free: slot = cursor[d] + chunkBase[c][d] + localrank.
// ONE 16 B scattered write per edge.
// rec = {src, fp32 coef = att*norm[src], ef01 bf16x2, ef23 bf16x2}
__global__ __launch_bounds__(256) void k_fill(
    const int* __restrict__ srcE, const int* __restrict__ dstE,
    const int* __restrict__ srcA, const int* __restrict__ dstA,
    const float* __restrict__ ef, const float* __restrict__ Watt,
    const float* __restrict__ batt, const float* __restrict__ norm,
    const int* __restrict__ cursor, const unsigned char* __restrict__ hist8,
    const unsigned short* __restrict__ rank16,
    uint4* __restrict__ rec) {
  int e = blockIdx.x * 256 + threadIdx.x;
  if (e >= ET) return;
  int s, d;
  float att;
  float4 f;
  if (e < EM) {
    s = srcE[e]; d = dstE[e];
    f = ((const float4*)ef)[e];
    float z = f.x * Watt[0] + f.y * Watt[1] + f.z * Watt[2] + f.w * Watt[3] + batt[0];
    att = 1.0f / (1.0f + __expf(-z));
  } else {
    int ea = e - EM;
    s = srcA[ea]; d = dstA[ea];
    f = make_float4(0.f, 0.f, 0.f, 0.f);
    att = 1.0f / (1.0f + __expf(-batt[0]));
  }
  float c = att * norm[s];
  unsigned rr = rank16[e];
  int slot = cursor[d] + (int)hist8[(size_t)(rr >> 9) * PITCHB + d]
           + (int)(rr & 511u);
  rec[slot] = make_uint4((unsigned)s, __float_as_uint(c),
                         pack_bf16x2(f.x, f.y), pack_bf16x2(f.z, f.w));
}

// Fused pull + GEMM. Block = 64 output rows, 4 waves.
// Phase 1: each wave pulls 16 nodes (gather featsb rows weighted by rec coef,
// redundant-lane ef-sum), writes the bf16 rst row into LDS [64][68] (pitch 68
// dwords: 16 B-aligned rows, bank-balanced ds_read_b128 in phase 2).
// Phase 2: MFMA GEMM; A(ks 0..3) = rst from LDS, A(ks 4..7) = featsb global.
// Eliminates the 51.2 MB rstb HBM round-trip and one dispatch. dst feature
// row now comes from featsb (bf16) instead of fp32 feats (-51.2 MB fetch).
__global__ __launch_bounds__(256, 4) void k_pullgemm(
    const unsigned* __restrict__ featsb,
    const unsigned* __restrict__ cnt, const int* __restrict__ cursor,
    const float* __restrict__ norm, const uint4* __restrict__ rec,
    const float* __restrict__ Wedge, const float* __restrict__ bedge,
    const unsigned* __restrict__ Wb,
    const float* __restrict__ bmsg, const float* __restrict__ bskip,
    float* __restrict__ out) {
  __shared__ unsigned lA[64 * 68];
  int lane = threadIdx.x & 63, wid = threadIdx.x >> 6;
  int rowt = blockIdx.x * 64;

  // hoisted per-lane constants for the pull epilogue
  float4 wa = ((const float4*)Wedge)[2 * lane + 0];
  float4 wb = ((const float4*)Wedge)[2 * lane + 1];
  float2 be = ((const float2*)bedge)[lane];

  // ---- phase 1: pull 16 nodes per wave into LDS ----
  for (int i = 0; i < 16; ++i) {
    int rloc = wid * 16 + i;
    int n = rowt + rloc;
    float rx = 0.f, ry = 0.f;
    if (n < NN) {
      int beg = __builtin_amdgcn_readfirstlane(cursor[n]);
      int len = __builtin_amdgcn_readfirstlane((int)cnt[n]);
      int end = beg + len;
      float2 acc = make_float2(0.f, 0.f);
      float4 efa = make_float4(0.f, 0.f, 0.f, 0.f);
      int e = beg;
      for (; e + 8 <= end; e += 8) {
        uint4 r0 = rec[e+0], r1 = rec[e+1], r2 = rec[e+2], r3 = rec[e+3];
        uint4 r4 = rec[e+4], r5 = rec[e+5], r6 = rec[e+6], r7 = rec[e+7];
        unsigned u0 = featsb[r0.x * 64 + lane];
        unsigned u1 = featsb[r1.x * 64 + lane];
        unsigned u2 = featsb[r2.x * 64 + lane];
        unsigned u3 = featsb[r3.x * 64 + lane];
        unsigned u4 = featsb[r4.x * 64 + lane];
        unsigned u5 = featsb[r5.x * 64 + lane];
        unsigned u6 = featsb[r6.x * 64 + lane];
        unsigned u7 = featsb[r7.x * 64 + lane];
        float c0 = __uint_as_float(r0.y), c1 = __uint_as_float(r1.y);
        float c2 = __uint_as_float(r2.y), c3 = __uint_as_float(r3.y);
        float c4 = __uint_as_float(r4.y), c5 = __uint_as_float(r5.y);
        float c6 = __uint_as_float(r6.y), c7 = __uint_as_float(r7.y);
        acc.x += c0 * UNP_LO(u0) + c1 * UNP_LO(u1) + c2 * UNP_LO(u2)
               + c3 * UNP_LO(u3) + c4 * UNP_LO(u4) + c5 * UNP_LO(u5)
               + c6 * UNP_LO(u6) + c7 * UNP_LO(u7);
        acc.y += c0 * UNP_HI(u0) + c1 * UNP_HI(u1) + c2 * UNP_HI(u2)
               + c3 * UNP_HI(u3) + c4 * UNP_HI(u4) + c5 * UNP_HI(u5)
               + c6 * UNP_HI(u6) + c7 * UNP_HI(u7);
        efa.x += UNP_LO(r0.z) + UNP_LO(r1.z) + UNP_LO(r2.z) + UNP_LO(r3.z)
               + UNP_LO(r4.z) + UNP_LO(r5.z) + UNP_LO(r6.z) + UNP_LO(r7.z);
        efa.y += UNP_HI(r0.z) + UNP_HI(r1.z) + UNP_HI(r2.z) + UNP_HI(r3.z)
               + UNP_HI(r4.z) + UNP_HI(r5.z) + UNP_HI(r6.z) + UNP_HI(r7.z);
        efa.z += UNP_LO(r0.w) + UNP_LO(r1.w) + UNP_LO(r2.w) + UNP_LO(r3.w)
               + UNP_LO(r4.w) + UNP_LO(r5.w) + UNP_LO(r6.w) + UNP_LO(r7.w);
        efa.w += UNP_HI(r0.w) + UNP_HI(r1.w) + UNP_HI(r2.w) + UNP_HI(r3.w)
               + UNP_HI(r4.w) + UNP_HI(r5.w) + UNP_HI(r6.w) + UNP_HI(r7.w);
      }
      for (; e < end; ++e) {
        uint4 r = rec[e];
        unsigned u = featsb[r.x * 64 + lane];
        float c = __uint_as_float(r.y);
        acc.x += c * UNP_LO(u);
        acc.y += c * UNP_HI(u);
        efa.x += UNP_LO(r.z); efa.y += UNP_HI(r.z);
        efa.z += UNP_LO(r.w); efa.w += UNP_HI(r.w);
      }
      float flen = (float)len;
      float nm = norm[n];
      unsigned ud = featsb[n * 64 + lane];   // dst row in bf16 (was fp32 feats)
      float fx = UNP_LO(ud), fy = UNP_HI(ud);
      float tx = wa.x * efa.x + wa.y * efa.y + wa.z * efa.z + wa.w * efa.w;
      float ty = wb.x * efa.x + wb.y * efa.y + wb.z * efa.z + wb.w * efa.w;
      rx = (acc.x + tx + flen * (be.x + nm * fx)) * nm;
      ry = (acc.y + ty + flen * (be.y + nm * fy)) * nm;
    }
    lA[rloc * 68 + lane] = pack_bf16x2(rx, ry);
  }
  __syncthreads();

  // ---- phase 2: GEMM out[64][128] = [rst | featsb] @ Wb^T-ish + bias ----
  int quad = lane >> 4, l15 = lane & 15;
  int rloc0 = wid * 16 + l15;
  int m0 = rowt + rloc0;

  f32x4 acc0[8];
#pragma unroll
  for (int ct = 0; ct < 8; ++ct) acc0[ct] = (f32x4){0.f, 0.f, 0.f, 0.f};

#pragma unroll
  for (int ks = 0; ks < 8; ++ks) {
    int kb = ks * 32;
    bf16x8 a0;
    if (ks < 4) {
      int off = ks * 16 + quad * 4;
      a0 = *(const bf16x8*)(&lA[rloc0 * 68 + off]);
    } else {
      int off = ((kb & 127) >> 1) + quad * 4;
      a0 = *(const bf16x8*)(featsb + (size_t)m0 * 64 + off);
    }
#pragma unroll
    for (int ct = 0; ct < 8; ++ct) {
      int j = ct * 16 + l15;
      bf16x8 b = *(const bf16x8*)(Wb + j * 128 + (kb >> 1) + quad * 4);
      acc0[ct] = __builtin_amdgcn_mfma_f32_16x16x32_bf16(a0, b, acc0[ct], 0, 0, 0);
    }
  }

#pragma unroll
  for (int ct = 0; ct < 8; ++ct) {
    int col = ct * 16 + l15;
    float bia = bmsg[col] + bskip[col];
#pragma unroll
    for (int r = 0; r < 4; ++r) {
      int row0 = rowt + wid * 16 + quad * 4 + r;
      if (row0 < NN) out[row0 * 128 + col] = acc0[ct][r] + bia;
    }
  }
}

extern "C" void kernel_launch(void* const* d_in, const int* in_sizes, int n_in,
                              void* d_out, int out_size, void* d_ws, size_t ws_size,
                              hipStream_t stream) {
  const float* feats  = (const float*)d_in[0];
  const float* ef     = (const float*)d_in[1];
  const int*   srcE   = (const int*)d_in[2];
  const int*   dstE   = (const int*)d_in[3];
  const int*   srcA   = (const int*)d_in[4];
  const int*   dstA   = (const int*)d_in[5];
  const float* Wskip  = (const float*)d_in[6];
  const float* bskip  = (const float*)d_in[7];
  const float* Wmsg   = (const float*)d_in[8];
  const float* bmsg   = (const float*)d_in[9];
  const float* Wedge  = (const float*)d_in[10];
  const float* bedge  = (const float*)d_in[11];
  const float* Watt   = (const float*)d_in[12];
  const float* batt   = (const float*)d_in[13];
  float* out = (float*)d_out;
  float* ws  = (float*)d_ws;

  float*          norm   = ws + OFF_NORM;
  unsigned*       cnt    = (unsigned*)(ws + OFF_CNT);
  int*            cursor = (int*)(ws + OFF_CUR);
  int*            bsum   = (int*)(ws + OFF_BSUM);
  unsigned*       Wb     = (unsigned*)(ws + OFF_WB);
  uint4*          rec    = (uint4*)(ws + OFF_REC);
  unsigned*       featsb = (unsigned*)(ws + OFF_FB);
  unsigned short* rank16 = (unsigned short*)(ws + OFF_RANK);

  unsigned*       hist8w = (unsigned*)(ws + OFF_HIST);
  unsigned*       deg8w  = hist8w + (size_t)HC * PITCHW;
  unsigned char*  hist8b = (unsigned char*)hist8w;
  unsigned char*  deg8b  = (unsigned char*)deg8w;

  k_hist<<<2 * HC, 1024, 0, stream>>>(srcE, dstE, dstA, feats, featsb,
                                      hist8w, deg8w, rank16);
  k_merge_wt<<<(NN + 255) / 256, 256, 0, stream>>>(hist8b, deg8b, cnt, norm,
                                                   Wmsg, Wskip, Wb);
  k_scan1<<<SB, 1024, 0, stream>>>(cnt, bsum);
  k_scan2<<<1, 64, 0, stream>>>(bsum);
  k_scan3<<<SB, 1024, 0, stream>>>(cnt, bsum, cursor);
  k_fill<<<(ET + 255) / 256, 256, 0, stream>>>(srcE, dstE, srcA, dstA, ef, Watt,
                                               batt, norm, cursor, hist8b,
                                               rank16, rec);
  k_pullgemm<<<NP / 64, 256, 0, stream>>>(featsb, cnt, cursor, norm, rec,
                                          Wedge, bedge, Wb, bmsg, bskip, out);
}

// Round 6
// 370.012 us; speedup vs baseline: 1.1220x; 1.1220x over previous
//
#include <hip/hip_runtime.h>
#include <hip/hip_bf16.h>

#define NN 100000
#define NP 100096            // 782 * 128, padded row count for GEMM
#define EM 1600000
#define EA 200000
#define ET (EM + EA)
#define SB 98                // scan blocks of 1024 nodes: 98*1024 >= NN

#define HC 128               // chunks per histogram
#define CNT_CHUNK 14063      // 128*14063 = 1800064 >= ET
#define DEG_CHUNK 12500      // 128*12500 = EM exactly
#define PITCHW 25024         // dwords per histogram slice (= 100096 B >= NN)
#define PITCHB 100096        // bytes per slice

// ws layout (4B units):
//  norm[NN] | cnt[NN] | cursor[NN] | bsum[128] | Wb[16384] |
//  rec[ET] uint4 | featsb[64*NP] | rstb[64*NP] | rank16[ET] ushort
// rstb region doubles as hist8 (128*PITCHW) + deg8 (128*PITCHW) before k_pull.
#define OFF_NORM 0
#define OFF_CNT  (NN)
#define OFF_CUR  (2*NN)
#define OFF_BSUM (3*NN)
#define OFF_WB   (3*NN + 128)
#define OFF_REC  (OFF_WB + 16384)    // 16B-aligned
#define OFF_FB   (OFF_REC + 4*ET)
#define OFF_RB   (OFF_FB + 64*NP)
#define OFF_RANK (OFF_RB + 64*NP)

#define UNP_LO(u) __uint_as_float((u) << 16)
#define UNP_HI(u) __uint_as_float((u) & 0xFFFF0000u)

typedef __attribute__((ext_vector_type(8))) short bf16x8;
typedef __attribute__((ext_vector_type(4))) float f32x4;

static __device__ __forceinline__ unsigned pack_bf16x2(float a, float b) {
  union { __hip_bfloat162 v; unsigned u; } cv;
  cv.v = __float22bfloat162_rn(make_float2(a, b));
  return cv.u;
}

// Histogram without global atomics (LDS byte counters) + fused feats->bf16
// convert. Blocks 0..127: dst-histogram over edge chunk c; byte-in-word LDS
// atomicAdd old value = local rank. Blocks 128..255: src-histogram (deg).
__global__ __launch_bounds__(1024) void k_hist(
    const int* __restrict__ srcE, const int* __restrict__ dstE,
    const int* __restrict__ dstA, const float* __restrict__ feats,
    unsigned* __restrict__ featsb,
    unsigned* __restrict__ hist8w, unsigned* __restrict__ deg8w,
    unsigned short* __restrict__ rank16) {
  __shared__ unsigned h[PITCHW];
  int tid = threadIdx.x;
  int bid = blockIdx.x;

  // fused convert: grid-stride over NP*64 dwords (2*HC*1024 = 262144 threads)
  for (int i = bid * 1024 + tid; i < NP * 64; i += 2 * HC * 1024) {
    if (i < NN * 64) {
      float2 f = ((const float2*)feats)[i];
      featsb[i] = pack_bf16x2(f.x, f.y);
    } else {
      featsb[i] = 0u;
    }
  }

  for (int i = tid; i < PITCHW; i += 1024) h[i] = 0u;
  __syncthreads();
  if (bid < HC) {
    int c = bid;
    int e1 = c * CNT_CHUNK + CNT_CHUNK; if (e1 > ET) e1 = ET;
    for (int e = c * CNT_CHUNK + tid; e < e1; e += 1024) {
      int d = (e < EM) ? dstE[e] : dstA[e - EM];
      unsigned sh = 8u * (unsigned)(d & 3);
      unsigned old = atomicAdd(&h[d >> 2], 1u << sh);
      unsigned lr = (old >> sh) & 255u;
      rank16[e] = (unsigned short)(((unsigned)c << 9) | lr);
    }
    __syncthreads();
    unsigned* dst = hist8w + (size_t)c * PITCHW;
    for (int i = tid; i < PITCHW; i += 1024) dst[i] = h[i];
  } else {
    int c = bid - HC;
    int e1 = c * DEG_CHUNK + DEG_CHUNK;
    for (int e = c * DEG_CHUNK + tid; e < e1; e += 1024) {
      int s = srcE[e];
      atomicAdd(&h[s >> 2], 1u << (8u * (unsigned)(s & 3)));
    }
    __syncthreads();
    unsigned* dst = deg8w + (size_t)c * PITCHW;
    for (int i = tid; i < PITCHW; i += 1024) dst[i] = h[i];
  }
}

// SWAR merge: each thread owns ONE DWORD = 4 nodes. Exclusive prefix over the
// 128 cnt slices in place (byte lanes never carry: per-node totals < 256),
// total -> cnt; deg slices summed -> norm = rsqrt. Fuses the old k_scan1:
// block b covers nodes [1024b, 1024b+1024) exactly, so an in-block reduction
// of the 4-byte totals yields bsum[b] directly. Also builds Wb.
__global__ __launch_bounds__(256) void k_merge_wt(
    unsigned* __restrict__ hist8w, const unsigned* __restrict__ deg8w,
    unsigned* __restrict__ cnt, float* __restrict__ norm,
    int* __restrict__ bsum,
    const float* __restrict__ Wmsg, const float* __restrict__ Wskip,
    unsigned* __restrict__ Wb) {
  __shared__ int ws4[4];
  int tid = threadIdx.x;
  int i = blockIdx.x * 256 + tid;      // dword-group index (4 nodes)
  int tot = 0;
  if (i < PITCHW) {
    unsigned t4 = 0;
#pragma unroll 16
    for (int c = 0; c < HC; ++c) {
      unsigned* p = hist8w + (size_t)c * PITCHW + i;
      unsigned w = *p;
      *p = t4;
      t4 += w;                          // SWAR: independent byte lanes
    }
    unsigned d4 = 0;
#pragma unroll 16
    for (int c = 0; c < HC; ++c) d4 += deg8w[(size_t)c * PITCHW + i];
    int n0 = i * 4;
#pragma unroll
    for (int k = 0; k < 4; ++k) {
      unsigned b = (t4 >> (8 * k)) & 255u;
      tot += (int)b;                    // bytes past NN are zero
      if (n0 + k < NN) {
        cnt[n0 + k] = b;
        unsigned dg = (d4 >> (8 * k)) & 255u;
        norm[n0 + k] = dg ? rsqrtf((float)dg) : 0.0f;
      }
    }
  }
  int lane = tid & 63, wid = tid >> 6;
#pragma unroll
  for (int s = 1; s < 64; s <<= 1) tot += __shfl_xor(tot, s, 64);
  if (lane == 0) ws4[wid] = tot;
  __syncthreads();
  if (tid == 0) bsum[blockIdx.x] = ws4[0] + ws4[1] + ws4[2] + ws4[3];

  if (i < 16384) {
    int j = i >> 7, kk = i & 127;   // kk = uint index within row (2 bf16)
    float a, b;
    if (kk < 64) {
      a = Wmsg[j * 128 + 2 * kk];
      b = Wmsg[j * 128 + 2 * kk + 1];
    } else {
      a = Wskip[j * 128 + 2 * kk - 128];
      b = Wskip[j * 128 + 2 * kk - 127];
    }
    Wb[j * 128 + kk] = pack_bf16x2(a, b);
  }
}

__global__ __launch_bounds__(64) void k_scan2(int* __restrict__ bsum) {
  int lane = threadIdx.x;
  int v0 = (lane < SB) ? bsum[lane] : 0;
  int v1 = (64 + lane < SB) ? bsum[64 + lane] : 0;
  int x0 = v0, x1 = v1;
#pragma unroll
  for (int s = 1; s < 64; s <<= 1) {
    int y = __shfl_up(x0, s, 64); if (lane >= s) x0 += y;
  }
#pragma unroll
  for (int s = 1; s < 64; s <<= 1) {
    int y = __shfl_up(x1, s, 64); if (lane >= s) x1 += y;
  }
  int t0 = __shfl(x0, 63, 64);
  if (lane < SB) bsum[lane] = x0 - v0;
  if (64 + lane < SB) bsum[64 + lane] = t0 + x1 - v1;
}

__global__ __launch_bounds__(1024) void k_scan3(const unsigned* __restrict__ cnt,
                                                const int* __restrict__ bsum,
                                                int* __restrict__ cursor) {
  __shared__ int ws16[16];
  int tid = threadIdx.x, lane = tid & 63, wid = tid >> 6;
  int i = blockIdx.x * 1024 + tid;
  int v = (i < NN) ? (int)cnt[i] : 0;
  int x = v;
#pragma unroll
  for (int s = 1; s < 64; s <<= 1) {
    int y = __shfl_up(x, s, 64); if (lane >= s) x += y;
  }
  if (lane == 63) ws16[wid] = x;
  __syncthreads();
  if (tid == 0) {
    int a = bsum[blockIdx.x];
#pragma unroll
    for (int w = 0; w < 16; ++w) { int t = ws16[w]; ws16[w] = a; a += t; }
  }
  __syncthreads();
  if (i < NN) cursor[i] = ws16[wid] + x - v;   // exclusive start of bucket
}

// bucket by dst, atomic-free: slot = cursor[d] + chunkBase[c][d] + localrank.
// ONE 16 B scattered write per edge.
// rec = {src, fp32 coef = att*norm[src], ef01 bf16x2, ef23 bf16x2}
__global__ __launch_bounds__(256) void k_fill(
    const int* __restrict__ srcE, const int* __restrict__ dstE,
    const int* __restrict__ srcA, const int* __restrict__ dstA,
    const float* __restrict__ ef, const float* __restrict__ Watt,
    const float* __restrict__ batt, const float* __restrict__ norm,
    const int* __restrict__ cursor, const unsigned char* __restrict__ hist8,
    const unsigned short* __restrict__ rank16,
    uint4* __restrict__ rec) {
  int e = blockIdx.x * 256 + threadIdx.x;
  if (e >= ET) return;
  int s, d;
  float att;
  float4 f;
  if (e < EM) {
    s = srcE[e]; d = dstE[e];
    f = ((const float4*)ef)[e];
    float z = f.x * Watt[0] + f.y * Watt[1] + f.z * Watt[2] + f.w * Watt[3] + batt[0];
    att = 1.0f / (1.0f + __expf(-z));
  } else {
    int ea = e - EM;
    s = srcA[ea]; d = dstA[ea];
    f = make_float4(0.f, 0.f, 0.f, 0.f);
    att = 1.0f / (1.0f + __expf(-batt[0]));
  }
  float c = att * norm[s];
  unsigned rr = rank16[e];
  int slot = cursor[d] + (int)hist8[(size_t)(rr >> 9) * PITCHB + d]
           + (int)(rr & 511u);
  rec[slot] = make_uint4((unsigned)s, __float_as_uint(c),
                         pack_bf16x2(f.x, f.y), pack_bf16x2(f.z, f.w));
}

// Pull only: 1 wave per node, no LDS, no barriers -> max waves/CU for latency
// hiding. dst feature row comes from featsb (bf16; validated in round 5),
// removing the 51.2 MB fp32 feats re-read. Writes rst row as packed bf16.
__global__ __launch_bounds__(256) void k_pull(
    const unsigned* __restrict__ featsb,
    const unsigned* __restrict__ cnt, const int* __restrict__ cursor,
    const float* __restrict__ norm, const uint4* __restrict__ rec,
    const float* __restrict__ Wedge, const float* __restrict__ bedge,
    unsigned* __restrict__ rstb) {
  int lane = threadIdx.x & 63, wid = threadIdx.x >> 6;
  int n = blockIdx.x * 4 + wid;
  if (n >= NP) return;
  if (n >= NN) { rstb[n * 64 + lane] = 0u; return; }

  int beg = __builtin_amdgcn_readfirstlane(cursor[n]);
  int len = __builtin_amdgcn_readfirstlane((int)cnt[n]);
  int end = beg + len;
  float2 acc = make_float2(0.f, 0.f);
  float4 efa = make_float4(0.f, 0.f, 0.f, 0.f);
  int e = beg;
  for (; e + 8 <= end; e += 8) {
    uint4 r0 = rec[e+0], r1 = rec[e+1], r2 = rec[e+2], r3 = rec[e+3];
    uint4 r4 = rec[e+4], r5 = rec[e+5], r6 = rec[e+6], r7 = rec[e+7];
    unsigned u0 = featsb[r0.x * 64 + lane];
    unsigned u1 = featsb[r1.x * 64 + lane];
    unsigned u2 = featsb[r2.x * 64 + lane];
    unsigned u3 = featsb[r3.x * 64 + lane];
    unsigned u4 = featsb[r4.x * 64 + lane];
    unsigned u5 = featsb[r5.x * 64 + lane];
    unsigned u6 = featsb[r6.x * 64 + lane];
    unsigned u7 = featsb[r7.x * 64 + lane];
    float c0 = __uint_as_float(r0.y), c1 = __uint_as_float(r1.y);
    float c2 = __uint_as_float(r2.y), c3 = __uint_as_float(r3.y);
    float c4 = __uint_as_float(r4.y), c5 = __uint_as_float(r5.y);
    float c6 = __uint_as_float(r6.y), c7 = __uint_as_float(r7.y);
    acc.x += c0 * UNP_LO(u0) + c1 * UNP_LO(u1) + c2 * UNP_LO(u2) + c3 * UNP_LO(u3)
           + c4 * UNP_LO(u4) + c5 * UNP_LO(u5) + c6 * UNP_LO(u6) + c7 * UNP_LO(u7);
    acc.y += c0 * UNP_HI(u0) + c1 * UNP_HI(u1) + c2 * UNP_HI(u2) + c3 * UNP_HI(u3)
           + c4 * UNP_HI(u4) + c5 * UNP_HI(u5) + c6 * UNP_HI(u6) + c7 * UNP_HI(u7);
    efa.x += UNP_LO(r0.z) + UNP_LO(r1.z) + UNP_LO(r2.z) + UNP_LO(r3.z)
           + UNP_LO(r4.z) + UNP_LO(r5.z) + UNP_LO(r6.z) + UNP_LO(r7.z);
    efa.y += UNP_HI(r0.z) + UNP_HI(r1.z) + UNP_HI(r2.z) + UNP_HI(r3.z)
           + UNP_HI(r4.z) + UNP_HI(r5.z) + UNP_HI(r6.z) + UNP_HI(r7.z);
    efa.z += UNP_LO(r0.w) + UNP_LO(r1.w) + UNP_LO(r2.w) + UNP_LO(r3.w)
           + UNP_LO(r4.w) + UNP_LO(r5.w) + UNP_LO(r6.w) + UNP_LO(r7.w);
    efa.w += UNP_HI(r0.w) + UNP_HI(r1.w) + UNP_HI(r2.w) + UNP_HI(r3.w)
           + UNP_HI(r4.w) + UNP_HI(r5.w) + UNP_HI(r6.w) + UNP_HI(r7.w);
  }
  for (; e < end; ++e) {
    uint4 r = rec[e];
    unsigned u = featsb[r.x * 64 + lane];
    float c = __uint_as_float(r.y);
    acc.x += c * UNP_LO(u);
    acc.y += c * UNP_HI(u);
    efa.x += UNP_LO(r.z); efa.y += UNP_HI(r.z);
    efa.z += UNP_LO(r.w); efa.w += UNP_HI(r.w);
  }
  float flen = (float)len;
  float nm = norm[n];
  unsigned ud = featsb[n * 64 + lane];
  float fx = UNP_LO(ud), fy = UNP_HI(ud);
  float4 wa = ((const float4*)Wedge)[2 * lane + 0];
  float4 wb = ((const float4*)Wedge)[2 * lane + 1];
  float2 be = ((const float2*)bedge)[lane];
  float tx = wa.x * efa.x + wa.y * efa.y + wa.z * efa.z + wa.w * efa.w;
  float ty = wb.x * efa.x + wb.y * efa.y + wb.z * efa.z + wb.w * efa.w;
  float rx = (acc.x + tx + flen * (be.x + nm * fx)) * nm;
  float ry = (acc.y + ty + flen * (be.y + nm * fy)) * nm;
  rstb[n * 64 + lane] = pack_bf16x2(rx, ry);
}

// MFMA GEMM: out[NN][128] = [rstb | featsb](bf16) @ Wb^T-ish + bias.
__global__ __launch_bounds__(256) void k_gemm(
    const unsigned* __restrict__ rstb, const unsigned* __restrict__ featsb,
    const unsigned* __restrict__ Wb,
    const float* __restrict__ bmsg, const float* __restrict__ bskip,
    float* __restrict__ out) {
  int lane = threadIdx.x & 63, wid = threadIdx.x >> 6;
  int quad = lane >> 4, l15 = lane & 15;
  int rowt = blockIdx.x * 128 + wid * 32;
  int m0 = rowt + l15;
  int m1 = m0 + 16;

  f32x4 acc0[8], acc1[8];
#pragma unroll
  for (int ct = 0; ct < 8; ++ct) {
    acc0[ct] = (f32x4){0.f, 0.f, 0.f, 0.f};
    acc1[ct] = (f32x4){0.f, 0.f, 0.f, 0.f};
  }

#pragma unroll
  for (int ks = 0; ks < 8; ++ks) {
    int kb = ks * 32;
    const unsigned* Xsrc = (kb < 128) ? rstb : featsb;
    int off = ((kb & 127) >> 1) + quad * 4;    // dword offset in 64-dword row
    bf16x8 a0 = *(const bf16x8*)(Xsrc + m0 * 64 + off);
    bf16x8 a1 = *(const bf16x8*)(Xsrc + m1 * 64 + off);
#pragma unroll
    for (int ct = 0; ct < 8; ++ct) {
      int j = ct * 16 + l15;
      bf16x8 b = *(const bf16x8*)(Wb + j * 128 + (kb >> 1) + quad * 4);
      acc0[ct] = __builtin_amdgcn_mfma_f32_16x16x32_bf16(a0, b, acc0[ct], 0, 0, 0);
      acc1[ct] = __builtin_amdgcn_mfma_f32_16x16x32_bf16(a1, b, acc1[ct], 0, 0, 0);
    }
  }

#pragma unroll
  for (int ct = 0; ct < 8; ++ct) {
    int col = ct * 16 + l15;
    float bia = bmsg[col] + bskip[col];
#pragma unroll
    for (int r = 0; r < 4; ++r) {
      int row0 = rowt + quad * 4 + r;
      if (row0 < NN) out[row0 * 128 + col] = acc0[ct][r] + bia;
      int row1 = row0 + 16;
      if (row1 < NN) out[row1 * 128 + col] = acc1[ct][r] + bia;
    }
  }
}

extern "C" void kernel_launch(void* const* d_in, const int* in_sizes, int n_in,
                              void* d_out, int out_size, void* d_ws, size_t ws_size,
                              hipStream_t stream) {
  const float* feats  = (const float*)d_in[0];
  const float* ef     = (const float*)d_in[1];
  const int*   srcE   = (const int*)d_in[2];
  const int*   dstE   = (const int*)d_in[3];
  const int*   srcA   = (const int*)d_in[4];
  const int*   dstA   = (const int*)d_in[5];
  const float* Wskip  = (const float*)d_in[6];
  const float* bskip  = (const float*)d_in[7];
  const float* Wmsg   = (const float*)d_in[8];
  const float* bmsg   = (const float*)d_in[9];
  const float* Wedge  = (const float*)d_in[10];
  const float* bedge  = (const float*)d_in[11];
  const float* Watt   = (const float*)d_in[12];
  const float* batt   = (const float*)d_in[13];
  float* out = (float*)d_out;
  float* ws  = (float*)d_ws;

  float*          norm   = ws + OFF_NORM;
  unsigned*       cnt    = (unsigned*)(ws + OFF_CNT);
  int*            cursor = (int*)(ws + OFF_CUR);
  int*            bsum   = (int*)(ws + OFF_BSUM);
  unsigned*       Wb     = (unsigned*)(ws + OFF_WB);
  uint4*          rec    = (uint4*)(ws + OFF_REC);
  unsigned*       featsb = (unsigned*)(ws + OFF_FB);
  unsigned*       rstb   = (unsigned*)(ws + OFF_RB);
  unsigned short* rank16 = (unsigned short*)(ws + OFF_RANK);

  // histogram slices overlay the rstb region (dead until k_pull rewrites it)
  unsigned*       hist8w = rstb;
  unsigned*       deg8w  = rstb + (size_t)HC * PITCHW;
  unsigned char*  hist8b = (unsigned char*)hist8w;

  k_hist<<<2 * HC, 1024, 0, stream>>>(srcE, dstE, dstA, feats, featsb,
                                      hist8w, deg8w, rank16);
  k_merge_wt<<<SB, 256, 0, stream>>>(hist8w, deg8w, cnt, norm, bsum,
                                     Wmsg, Wskip, Wb);
  k_scan2<<<1, 64, 0, stream>>>(bsum);
  k_scan3<<<SB, 1024, 0, stream>>>(cnt, bsum, cursor);
  k_fill<<<(ET + 255) / 256, 256, 0, stream>>>(srcE, dstE, srcA, dstA, ef, Watt,
                                               batt, norm, cursor, hist8b,
                                               rank16, rec);
  k_pull<<<NP / 4, 256, 0, stream>>>(featsb, cnt, cursor, norm,
                                     rec, Wedge, bedge, rstb);
  k_gemm<<<NP / 128, 256, 0, stream>>>(rstb, featsb, Wb, bmsg, bskip, out);
}